// Round 15
// baseline (215.553 us; speedup 1.0000x reference)
//
#include <hip/hip_runtime.h>
#include <hip/hip_bf16.h>

typedef __hip_bfloat16 bf16;
typedef __attribute__((ext_vector_type(8))) short short8;
typedef __attribute__((ext_vector_type(4))) float f32x4;

#define S_LEN 2048
#define BATCH 2
#define M_TOT 4096   // BATCH*S_LEN
#define HID 2048
#define NH 32
#define NKV 8
#define HD 64
#define KVD 512      // NKV*HD
#define QSCALE 0.125f

#define MFMA16(a, b, c) __builtin_amdgcn_mfma_f32_16x16x32_bf16(a, b, c, 0, 0, 0)

__device__ __forceinline__ void gload_lds16(const bf16* g, bf16* l) {
    __builtin_amdgcn_global_load_lds((const __attribute__((address_space(1))) void*)g,
                                     (__attribute__((address_space(3))) void*)l,
                                     16, 0, 0);
}

__device__ __forceinline__ float b2f(short v) {
    unsigned u = ((unsigned)(unsigned short)v) << 16;
    float f; __builtin_memcpy(&f, &u, 4); return f;
}

// ---------------- merged cast fp32 -> bf16 for all 5 inputs ----------------
#define N8_X   1048576   // 4096*2048/8
#define N8_WQ   524288   // 2048*2048/8
#define N8_WK   131072   // 512*2048/8
#define N8_TOT 2359296   // x+wq+wk+wv+wo
__global__ void cast_all_kernel(const float* __restrict__ x, const float* __restrict__ wq,
                                const float* __restrict__ wk, const float* __restrict__ wv,
                                const float* __restrict__ wo, bf16* __restrict__ dst) {
    int stride = gridDim.x * blockDim.x;
    for (int i = blockIdx.x * blockDim.x + threadIdx.x; i < N8_TOT; i += stride) {
        const float* s; int off;
        if (i < N8_X)                        { s = x;  off = i; }
        else if (i < N8_X + N8_WQ)           { s = wq; off = i - N8_X; }
        else if (i < N8_X + N8_WQ + N8_WK)   { s = wk; off = i - (N8_X + N8_WQ); }
        else if (i < N8_X + N8_WQ + 2*N8_WK) { s = wv; off = i - (N8_X + N8_WQ + N8_WK); }
        else                                 { s = wo; off = i - (N8_X + N8_WQ + 2*N8_WK); }
        const float4* sp = (const float4*)(s + (size_t)off * 8);
        float4 a = sp[0], b = sp[1];
        bf16 tmp[8];
        tmp[0] = __float2bfloat16(a.x); tmp[1] = __float2bfloat16(a.y);
        tmp[2] = __float2bfloat16(a.z); tmp[3] = __float2bfloat16(a.w);
        tmp[4] = __float2bfloat16(b.x); tmp[5] = __float2bfloat16(b.y);
        tmp[6] = __float2bfloat16(b.z); tmp[7] = __float2bfloat16(b.w);
        *(short8*)(dst + (size_t)i * 8) = *(short8*)tmp;
    }
}

// ---------------- RoPE tables: [S][32] cos, sin (fp32) ----------------
__global__ void rope_tables_kernel(float* __restrict__ cosb, float* __restrict__ sinb) {
    int idx = blockIdx.x * blockDim.x + threadIdx.x;
    if (idx >= S_LEN * 32) return;
    int s = idx >> 5, d = idx & 31;
    float freq = powf(10000.0f, -(float)(2 * d) / 64.0f);
    float ang = (float)s * freq;
    cosb[idx] = cosf(ang);
    sinb[idx] = sinf(ang);
}

// rope one 8-elem fragment (4 even/odd pairs); scale folded into output
__device__ __forceinline__ short8 rope8(short8 v, float4 c, float4 s, float scale) {
    short8 o;
    const float* cp = (const float*)&c;
    const float* sp = (const float*)&s;
    #pragma unroll
    for (int m = 0; m < 4; m++) {
        float xe = b2f(v[2 * m]) * scale;
        float xo = b2f(v[2 * m + 1]) * scale;
        bf16 oe = __float2bfloat16(xe * cp[m] - xo * sp[m]);
        bf16 oo = __float2bfloat16(xe * sp[m] + xo * cp[m]);
        short se, so;
        __builtin_memcpy(&se, &oe, 2); __builtin_memcpy(&so, &oo, 2);
        o[2 * m] = se; o[2 * m + 1] = so;
    }
    return o;
}

// ======== 256x256 / BK=64 / 8-wave QKV GEMM (proven 2-buf counted-vmcnt) ====
// Waves 2x4: wave w -> wr=w>>2 (row half), wc=w&3 (col quarter). Per-wave C:
// 128x64 = 8x4 frags of 16x16; acc = 128 VGPR. LDS 128 KiB (2 dbuf x A,B
// 256x64). Chunk swizzle: phys = chunk ^ (row&7), pre-swizzled global source.
// Schedule (R12-verified ordering): prologue stage(0),stage(1),vmcnt(8),bar;
// iter t: compute(buf t&1); vmcnt(0); barrier; stage(buf, t+2).
__global__ __launch_bounds__(512, 2) void gemm_qkv256_kernel(
        const bf16* __restrict__ xb,
        const bf16* __restrict__ wq, const bf16* __restrict__ wk, const bf16* __restrict__ wv,
        const float* __restrict__ cosb, const float* __restrict__ sinb,
        bf16* __restrict__ qb, bf16* __restrict__ kb, bf16* __restrict__ vtb) {
    __shared__ bf16 As[2][256 * 64];
    __shared__ bf16 Bs[2][256 * 64];
    int tid = threadIdx.x;
    int lane = tid & 63, w = tid >> 6;
    int wr = w >> 2, wc = w & 3;
    int lhi = lane >> 4, llo = lane & 15;

    int by = blockIdx.y;
    const bf16* W; int n0, mode;
    if (by < 8)       { W = wq; n0 = by * 256;        mode = 0; }
    else if (by < 10) { W = wk; n0 = (by - 8) * 256;  mode = 2; }
    else              { W = wv; n0 = (by - 10) * 256; mode = 1; }
    int bx = blockIdx.x;
    int bxs = (bx & 7) * 2 + (bx >> 3);    // XCD swizzle, 16 tiles bijective
    int m0 = bxs * 256;

    // staging: 4 chunks per operand per thread; global slot pre-swizzled
    const bf16 *gA[4], *gB[4];
    int dc[4];
    #pragma unroll
    for (int q = 0; q < 4; q++) {
        int c = tid + 512 * q;            // 0..2047
        int row = c >> 3;                 // 0..255
        int sl = (c & 7) ^ (row & 7);
        gA[q] = xb + (size_t)(m0 + row) * HID + sl * 8;
        gB[q] = W + (size_t)(n0 + row) * HID + sl * 8;
        dc[q] = c * 8;
    }
    auto stage = [&](int buf, int k0) {
        #pragma unroll
        for (int q = 0; q < 4; q++) gload_lds16(gA[q] + k0, &As[buf][dc[q]]);
        #pragma unroll
        for (int q = 0; q < 4; q++) gload_lds16(gB[q] + k0, &Bs[buf][dc[q]]);
    };

    f32x4 acc[8][4] = {};

    stage(0, 0);
    stage(1, 64);
    asm volatile("s_waitcnt vmcnt(8)" ::: "memory");   // tile 0 landed; tile 1 in flight
    __builtin_amdgcn_s_barrier();

    const int nt = HID / 64;   // 32
    for (int t = 0; t < nt; ++t) {
        int buf = t & 1;
        const bf16* Ac = &As[buf][0];
        const bf16* Bc = &Bs[buf][0];
        // B-frags for the whole tile: 4 cols x 2 k-chunks
        short8 bfr[4][2];
        #pragma unroll
        for (int j = 0; j < 4; j++) {
            int row = wc * 64 + j * 16 + llo;
            int x = row & 7;
            bfr[j][0] = *(const short8*)(Bc + row * 64 + ((lhi ^ x) * 8));
            bfr[j][1] = *(const short8*)(Bc + row * 64 + (((4 + lhi) ^ x) * 8));
        }
        #pragma unroll
        for (int i = 0; i < 8; i++) {
            int row = wr * 128 + i * 16 + llo;
            int x = row & 7;
            short8 a0 = *(const short8*)(Ac + row * 64 + ((lhi ^ x) * 8));
            short8 a1 = *(const short8*)(Ac + row * 64 + (((4 + lhi) ^ x) * 8));
            __builtin_amdgcn_s_setprio(1);
            #pragma unroll
            for (int j = 0; j < 4; j++)
                acc[i][j] = MFMA16(a0, bfr[j][0], acc[i][j]);
            #pragma unroll
            for (int j = 0; j < 4; j++)
                acc[i][j] = MFMA16(a1, bfr[j][1], acc[i][j]);
            __builtin_amdgcn_s_setprio(0);
        }
        asm volatile("s_waitcnt vmcnt(0)" ::: "memory");   // stage(t+1) complete
        __builtin_amdgcn_s_barrier();
        if (t + 2 < nt) stage(buf, (t + 2) * 64);          // buf's readers all done
    }

    // ---- epilogue ----
    #pragma unroll
    for (int i = 0; i < 8; i++)
        #pragma unroll
        for (int j = 0; j < 4; j++) {
            int col = wc * 64 + j * 16 + llo;
            #pragma unroll
            for (int r = 0; r < 4; r++) {
                int m = m0 + wr * 128 + i * 16 + lhi * 4 + r;
                float v = acc[i][j][r];
                if (mode == 0) {
                    qb[(size_t)m * 2048 + n0 + col] = __float2bfloat16(v);
                } else if (mode == 1) {
                    int bb = m >> 11, ss = m & 2047;
                    vtb[((size_t)(bb * 512 + n0 + col)) * S_LEN + ss] = __float2bfloat16(v);
                } else {
                    int dcol = n0 + col;
                    int dd = dcol & 63;
                    int pidx = dd >> 1;
                    float sgn = (dd & 1) ? 1.0f : -1.0f;
                    int ss = m & 2047;
                    float c  = cosb[ss * 32 + pidx];
                    float sn = sinb[ss * 32 + pidx];
                    float o = __shfl_xor(v, 1, 64);
                    kb[(size_t)m * 512 + dcol] = __float2bfloat16(v * c + sgn * o * sn);
                }
            }
        }
}

// ---------------- GEMM core: 128x128 tile, BK=32, 3-buffer depth-2 pipeline --
// (kept for gemm_out)
__device__ __forceinline__ void gemm_core(const bf16* __restrict__ A,
                                          const bf16* __restrict__ W,
                                          int K, int m0, int n0,
                                          bf16* As, bf16* Bs,
                                          f32x4 acc[4][4]) {
    int tid = threadIdx.x;
    int lane = tid & 63, wid = tid >> 6;
    int wr = wid >> 1, wc = wid & 1;
    int lhi = lane >> 4, llo = lane & 15;
    int c0 = tid, c1 = tid + 256;
    int r0 = c0 >> 2, s0 = ((c0 & 3) ^ ((r0 >> 1) & 3)) * 8;
    int r1 = c1 >> 2, s1 = ((c1 & 3) ^ ((r1 >> 1) & 3)) * 8;
    const bf16* gA0 = A + (size_t)(m0 + r0) * K + s0;
    const bf16* gA1 = A + (size_t)(m0 + r1) * K + s1;
    const bf16* gB0 = W + (size_t)(n0 + r0) * K + s0;
    const bf16* gB1 = W + (size_t)(n0 + r1) * K + s1;

    auto stage = [&](int buf, int k0) {
        bf16* a = As + buf * 4096;
        bf16* b = Bs + buf * 4096;
        gload_lds16(gA0 + k0, a + c0 * 8);
        gload_lds16(gA1 + k0, a + c1 * 8);
        gload_lds16(gB0 + k0, b + c0 * 8);
        gload_lds16(gB1 + k0, b + c1 * 8);
    };
    auto compute = [&](int buf) {
        const bf16* Ac = As + buf * 4096;
        const bf16* Bc = Bs + buf * 4096;
        short8 af[4], bfr[4];
        #pragma unroll
        for (int i = 0; i < 4; i++) {
            int row = wr * 64 + i * 16 + llo;
            af[i] = *(const short8*)(Ac + row * 32 + ((lhi ^ ((row >> 1) & 3)) * 8));
        }
        #pragma unroll
        for (int j = 0; j < 4; j++) {
            int row = wc * 64 + j * 16 + llo;
            bfr[j] = *(const short8*)(Bc + row * 32 + ((lhi ^ ((row >> 1) & 3)) * 8));
        }
        __builtin_amdgcn_s_setprio(1);
        #pragma unroll
        for (int i = 0; i < 4; i++)
            #pragma unroll
            for (int j = 0; j < 4; j++)
                acc[i][j] = MFMA16(af[i], bfr[j], acc[i][j]);
        __builtin_amdgcn_s_setprio(0);
    };

    int nt = K / 32;
    stage(0, 0);
    stage(1, 32);
    int b0 = 0, b1 = 1, b2 = 2;
    for (int t = 0; t < nt - 1; ++t) {
        asm volatile("s_waitcnt vmcnt(4)" ::: "memory");
        __builtin_amdgcn_s_barrier();
        if (t + 2 < nt) stage(b2, (t + 2) * 32);
        __builtin_amdgcn_sched_barrier(0);
        compute(b0);
        int tmp = b0; b0 = b1; b1 = b2; b2 = tmp;
    }
    asm volatile("s_waitcnt vmcnt(0)" ::: "memory");
    __builtin_amdgcn_s_barrier();
    compute(b0);
}

// ---------------- output projection: fp32 out ----------------
__global__ __launch_bounds__(256) void gemm_out_kernel(
        const bf16* __restrict__ attnb, const bf16* __restrict__ wob,
        float* __restrict__ out) {
    __shared__ bf16 As[3 * 128 * 32];
    __shared__ bf16 Bs[3 * 128 * 32];
    int bx = blockIdx.x;
    int bxs = (bx & 7) * 4 + (bx >> 3);
    int m0 = bxs * 128;
    int n0 = blockIdx.y * 128;
    f32x4 acc[4][4] = {};
    gemm_core(attnb, wob, HID, m0, n0, As, Bs, acc);

    int lane = threadIdx.x & 63, wid = threadIdx.x >> 6;
    int wr = wid >> 1, wc = wid & 1;
    int lhi = lane >> 4, llo = lane & 15;
    #pragma unroll
    for (int i = 0; i < 4; i++)
        #pragma unroll
        for (int j = 0; j < 4; j++) {
            int col = wc * 64 + j * 16 + llo;
            #pragma unroll
            for (int r = 0; r < 4; r++) {
                int row = wr * 64 + i * 16 + lhi * 4 + r;
                out[(size_t)(m0 + row) * HID + n0 + col] = acc[i][j][r];
            }
        }
}

// ---------------- flash attention: paired q-tiles, lean register budget -----
__global__ __launch_bounds__(256, 4) void flash_kernel(
        const bf16* __restrict__ qb, const bf16* __restrict__ kb,
        const bf16* __restrict__ vtb, const float* __restrict__ cosb,
        const float* __restrict__ sinb, bf16* __restrict__ attnb) {
    __shared__ bf16 Ks[2][64 * 64];
    __shared__ bf16 Vs[2][64 * 64];
    __shared__ bf16 Pl[4][16 * 64];
    int bh = blockIdx.y;
    int b = bh >> 5, h = bh & 31;
    int kvh = h >> 2;
    int tid = threadIdx.x;
    int wid = tid >> 6, lane = tid & 63;
    int lhi = lane >> 4, llo = lane & 15;
    int jA = blockIdx.x, jB = 31 - jA;

    const bf16* Kg = kb + (size_t)(b * S_LEN) * KVD + kvh * HD;
    const bf16* Vg = vtb + (size_t)(b * 512 + kvh * 64) * S_LEN;

    int c0 = tid, c1 = tid + 256;
    int r0 = c0 >> 3, s0 = ((c0 & 7) ^ (r0 & 7)) * 8;
    int r1 = c1 >> 3, s1 = ((c1 & 7) ^ (r1 & 7)) * 8;

    bf16* pl = &Pl[wid][0];
    const int xw = llo & 7;
    const int hh = lhi >> 1;
    bf16* pwb = pl + llo * 64 + (lhi & 1) * 4;
    const int prd0 = llo * 64 + ((lhi ^ xw) * 8);
    const int prd1 = llo * 64 + (((lhi + 4) ^ xw) * 8);

    auto stage = [&](int buf, int t0) {
        gload_lds16(Kg + (size_t)(t0 + r0) * KVD + s0, &Ks[buf][c0 * 8]);
        gload_lds16(Kg + (size_t)(t0 + r1) * KVD + s1, &Ks[buf][c1 * 8]);
        gload_lds16(Vg + (size_t)r0 * S_LEN + t0 + s0, &Vs[buf][c0 * 8]);
        gload_lds16(Vg + (size_t)r1 * S_LEN + t0 + s1, &Vs[buf][c1 * 8]);
    };

    int qrowA0 = jA * 64 + wid * 16;
    int qrowB0 = jB * 64 + wid * 16;
    short8 qfA0, qfA1, qfB0, qfB1;
    {
        int spos = qrowA0 + llo;
        const bf16* qr = qb + ((size_t)(b * S_LEN) + spos) * (NH * HD) + h * HD;
        float4 c0v = *(const float4*)(cosb + spos * 32 + lhi * 4);
        float4 s0v = *(const float4*)(sinb + spos * 32 + lhi * 4);
        float4 c1v = *(const float4*)(cosb + spos * 32 + 16 + lhi * 4);
        float4 s1v = *(const float4*)(sinb + spos * 32 + 16 + lhi * 4);
        qfA0 = rope8(*(const short8*)(qr + lhi * 8), c0v, s0v, QSCALE);
        qfA1 = rope8(*(const short8*)(qr + 32 + lhi * 8), c1v, s1v, QSCALE);
    }
    {
        int spos = qrowB0 + llo;
        const bf16* qr = qb + ((size_t)(b * S_LEN) + spos) * (NH * HD) + h * HD;
        float4 c0v = *(const float4*)(cosb + spos * 32 + lhi * 4);
        float4 s0v = *(const float4*)(sinb + spos * 32 + lhi * 4);
        float4 c1v = *(const float4*)(cosb + spos * 32 + 16 + lhi * 4);
        float4 s1v = *(const float4*)(sinb + spos * 32 + 16 + lhi * 4);
        qfB0 = rope8(*(const short8*)(qr + lhi * 8), c0v, s0v, QSCALE);
        qfB1 = rope8(*(const short8*)(qr + 32 + lhi * 8), c1v, s1v, QSCALE);
    }

    f32x4 accA[4] = {}, accB[4] = {};
    float psumA = 0.f, psumB = 0.f;
    int qloc = wid * 16 + llo;

    stage(0, 0);
    asm volatile("s_waitcnt vmcnt(0)" ::: "memory");
    __builtin_amdgcn_s_barrier();
    int cur = 0;
    for (int t = 0; t <= jB; ++t) {
        int t0 = t * 64;
        if (t < jB) stage(cur ^ 1, t0 + 64);
        const bf16* Kc = &Ks[cur][0];
        const bf16* Vc = &Vs[cur][0];
        bool doA = (t <= jA);
        f32x4 zA[4], zB[4];
        __builtin_amdgcn_s_setprio(1);
        #pragma unroll
        for (int cb = 0; cb < 4; cb++) {
            int row = cb * 16 + llo;
            short8 k0 = *(const short8*)(Kc + row * 64 + ((lhi ^ xw) * 8));
            short8 k1 = *(const short8*)(Kc + row * 64 + (((lhi + 4) ^ xw) * 8));
            f32x4 zz = {0.f, 0.f, 0.f, 0.f};
            zz = MFMA16(k0, qfB0, zz);
            zz = MFMA16(k1, qfB1, zz);
            zB[cb] = zz;
            if (doA) {
                f32x4 yy = {0.f, 0.f, 0.f, 0.f};
                yy = MFMA16(k0, qfA0, yy);
                yy = MFMA16(k1, qfA1, yy);
                zA[cb] = yy;
            }
        }
        __builtin_amdgcn_s_setprio(0);
        if (doA) {
            bool diag = (t == jA);
            #pragma unroll
            for (int cb = 0; cb < 4; cb++) {
                float p0 = __expf(zA[cb][0]);
                float p1 = __expf(zA[cb][1]);
                float p2 = __expf(zA[cb][2]);
                float p3 = __expf(zA[cb][3]);
                if (diag) {
                    int kl = cb * 16 + lhi * 4;
                    p0 = (kl + 0 <= qloc) ? p0 : 0.f;
                    p1 = (kl + 1 <= qloc) ? p1 : 0.f;
                    p2 = (kl + 2 <= qloc) ? p2 : 0.f;
                    p3 = (kl + 3 <= qloc) ? p3 : 0.f;
                }
                psumA += (p0 + p1) + (p2 + p3);
                bf16 tmp[4];
                tmp[0] = __float2bfloat16(p0); tmp[1] = __float2bfloat16(p1);
                tmp[2] = __float2bfloat16(p2); tmp[3] = __float2bfloat16(p3);
                *(uint2*)(pwb + (((2 * cb + hh) ^ xw) * 8)) = *(uint2*)tmp;
            }
            short8 pa0 = *(const short8*)(pl + prd0);
            short8 pa1 = *(const short8*)(pl + prd1);
            __builtin_amdgcn_s_setprio(1);
            #pragma unroll
            for (int jb = 0; jb < 4; jb++) {
                int row = jb * 16 + llo;
                short8 v0 = *(const short8*)(Vc + row * 64 + ((lhi ^ xw) * 8));
                short8 v1 = *(const short8*)(Vc + row * 64 + (((lhi + 4) ^ xw) * 8));
                accA[jb] = MFMA16(pa0, v0, accA[jb]);
                accA[jb] = MFMA16(pa1, v1, accA[jb]);
            }
            __builtin_amdgcn_s_setprio(0);
        }
        {
            bool diag = (t == jB);
            #pragma unroll
            for (int cb = 0; cb < 4; cb++) {
                float p0 = __expf(zB[cb][0]);
                float p1 = __expf(zB[cb][1]);
                float p2 = __expf(zB[cb][2]);
                float p3 = __expf(zB[cb][3]);
                if (diag) {
                    int kl = cb * 16 + lhi * 4;
                    p0 = (kl + 0 <= qloc) ? p0 : 0.f;
                    p1 = (kl + 1 <= qloc) ? p1 : 0.f;
                    p2 = (kl + 2 <= qloc) ? p2 : 0.f;
                    p3 = (kl + 3 <= qloc) ? p3 : 0.f;
                }
                psumB += (p0 + p1) + (p2 + p3);
                bf16 tmp[4];
                tmp[0] = __float2bfloat16(p0); tmp[1] = __float2bfloat16(p1);
                tmp[2] = __float2bfloat16(p2); tmp[3] = __float2bfloat16(p3);
                *(uint2*)(pwb + (((2 * cb + hh) ^ xw) * 8)) = *(uint2*)tmp;
            }
            short8 pb0 = *(const short8*)(pl + prd0);
            short8 pb1 = *(const short8*)(pl + prd1);
            __builtin_amdgcn_s_setprio(1);
            #pragma unroll
            for (int jb = 0; jb < 4; jb++) {
                int row = jb * 16 + llo;
                short8 v0 = *(const short8*)(Vc + row * 64 + ((lhi ^ xw) * 8));
                short8 v1 = *(const short8*)(Vc + row * 64 + (((lhi + 4) ^ xw) * 8));
                accB[jb] = MFMA16(pb0, v0, accB[jb]);
                accB[jb] = MFMA16(pb1, v1, accB[jb]);
            }
            __builtin_amdgcn_s_setprio(0);
        }
        asm volatile("s_waitcnt vmcnt(0)" ::: "memory");
        __builtin_amdgcn_s_barrier();
        cur ^= 1;
    }
    psumA += __shfl_xor(psumA, 16, 64);
    psumA += __shfl_xor(psumA, 32, 64);
    psumB += __shfl_xor(psumB, 16, 64);
    psumB += __shfl_xor(psumB, 32, 64);
    float invA[4], invB[4];
    #pragma unroll
    for (int r = 0; r < 4; r++) {
        invA[r] = 1.0f / __shfl(psumA, lhi * 4 + r, 64);
        invB[r] = 1.0f / __shfl(psumB, lhi * 4 + r, 64);
    }
    size_t obaseA = ((size_t)(b * S_LEN) + qrowA0) * (NH * HD) + h * HD;
    size_t obaseB = ((size_t)(b * S_LEN) + qrowB0) * (NH * HD) + h * HD;
    #pragma unroll
    for (int jb = 0; jb < 4; jb++)
        #pragma unroll
        for (int r = 0; r < 4; r++) {
            int row = lhi * 4 + r;
            attnb[obaseA + (size_t)row * (NH * HD) + jb * 16 + llo] =
                __float2bfloat16(accA[jb][r] * invA[r]);
            attnb[obaseB + (size_t)row * (NH * HD) + jb * 16 + llo] =
                __float2bfloat16(accB[jb][r] * invB[r]);
        }
}

// ---------------- launcher ----------------
extern "C" void kernel_launch(void* const* d_in, const int* in_sizes, int n_in,
                              void* d_out, int out_size, void* d_ws, size_t ws_size,
                              hipStream_t stream) {
    const float* x  = (const float*)d_in[0];
    const float* wq = (const float*)d_in[1];
    const float* wk = (const float*)d_in[2];
    const float* wv = (const float*)d_in[3];
    const float* wo = (const float*)d_in[4];
    float* out = (float*)d_out;

    char* ws = (char*)d_ws;
    size_t off = 0;
    auto alloc = [&](size_t bytes) { void* p = ws + off; off += (bytes + 255) & ~(size_t)255; return p; };
    // NOTE: xb..wob must stay CONTIGUOUS (cast_all writes them as one region)
    bf16* xb   = (bf16*)alloc((size_t)M_TOT * HID * 2);
    bf16* wqb  = (bf16*)alloc((size_t)HID * HID * 2);
    bf16* wkb  = (bf16*)alloc((size_t)512 * HID * 2);
    bf16* wvb  = (bf16*)alloc((size_t)512 * HID * 2);
    bf16* wob  = (bf16*)alloc((size_t)HID * HID * 2);
    bf16* qb   = (bf16*)alloc((size_t)M_TOT * 2048 * 2);
    bf16* kb   = (bf16*)alloc((size_t)M_TOT * 512 * 2);
    bf16* vtb  = (bf16*)alloc((size_t)M_TOT * 512 * 2);
    bf16* attnb= (bf16*)alloc((size_t)M_TOT * 2048 * 2);
    float* cosb= (float*)alloc((size_t)S_LEN * 32 * 4);
    float* sinb= (float*)alloc((size_t)S_LEN * 32 * 4);

    cast_all_kernel<<<2048, 256, 0, stream>>>(x, wq, wk, wv, wo, xb);

    rope_tables_kernel<<<(S_LEN * 32 + 255) / 256, 256, 0, stream>>>(cosb, sinb);

    gemm_qkv256_kernel<<<dim3(16, 12), 512, 0, stream>>>(xb, wqb, wkb, wvb,
                                                         cosb, sinb, qb, kb, vtb);

    flash_kernel<<<dim3(16, BATCH * NH), 256, 0, stream>>>(qb, kb, vtb, cosb, sinb, attnb);

    gemm_out_kernel<<<dim3(M_TOT / 128, HID / 128), 256, 0, stream>>>(attnb, wob, out);
}

// Round 16
// 214.146 us; speedup vs baseline: 1.0066x; 1.0066x over previous
//
#include <hip/hip_runtime.h>
#include <hip/hip_bf16.h>

typedef __hip_bfloat16 bf16;
typedef __attribute__((ext_vector_type(8))) short short8;
typedef __attribute__((ext_vector_type(4))) float f32x4;

#define S_LEN 2048
#define BATCH 2
#define M_TOT 4096   // BATCH*S_LEN
#define HID 2048
#define NH 32
#define NKV 8
#define HD 64
#define KVD 512      // NKV*HD
#define QSCALE 0.125f

#define MFMA16(a, b, c) __builtin_amdgcn_mfma_f32_16x16x32_bf16(a, b, c, 0, 0, 0)

__device__ __forceinline__ void gload_lds16(const bf16* g, bf16* l) {
    __builtin_amdgcn_global_load_lds((const __attribute__((address_space(1))) void*)g,
                                     (__attribute__((address_space(3))) void*)l,
                                     16, 0, 0);
}

__device__ __forceinline__ float b2f(short v) {
    unsigned u = ((unsigned)(unsigned short)v) << 16;
    float f; __builtin_memcpy(&f, &u, 4); return f;
}

// ---------------- merged cast fp32 -> bf16 for all 5 inputs ----------------
#define N8_X   1048576   // 4096*2048/8
#define N8_WQ   524288   // 2048*2048/8
#define N8_WK   131072   // 512*2048/8
#define N8_TOT 2359296   // x+wq+wk+wv+wo
__global__ void cast_all_kernel(const float* __restrict__ x, const float* __restrict__ wq,
                                const float* __restrict__ wk, const float* __restrict__ wv,
                                const float* __restrict__ wo, bf16* __restrict__ dst) {
    int stride = gridDim.x * blockDim.x;
    for (int i = blockIdx.x * blockDim.x + threadIdx.x; i < N8_TOT; i += stride) {
        const float* s; int off;
        if (i < N8_X)                        { s = x;  off = i; }
        else if (i < N8_X + N8_WQ)           { s = wq; off = i - N8_X; }
        else if (i < N8_X + N8_WQ + N8_WK)   { s = wk; off = i - (N8_X + N8_WQ); }
        else if (i < N8_X + N8_WQ + 2*N8_WK) { s = wv; off = i - (N8_X + N8_WQ + N8_WK); }
        else                                 { s = wo; off = i - (N8_X + N8_WQ + 2*N8_WK); }
        const float4* sp = (const float4*)(s + (size_t)off * 8);
        float4 a = sp[0], b = sp[1];
        bf16 tmp[8];
        tmp[0] = __float2bfloat16(a.x); tmp[1] = __float2bfloat16(a.y);
        tmp[2] = __float2bfloat16(a.z); tmp[3] = __float2bfloat16(a.w);
        tmp[4] = __float2bfloat16(b.x); tmp[5] = __float2bfloat16(b.y);
        tmp[6] = __float2bfloat16(b.z); tmp[7] = __float2bfloat16(b.w);
        *(short8*)(dst + (size_t)i * 8) = *(short8*)tmp;
    }
}

// ---------------- RoPE tables: [S][32] cos, sin (fp32) ----------------
__global__ void rope_tables_kernel(float* __restrict__ cosb, float* __restrict__ sinb) {
    int idx = blockIdx.x * blockDim.x + threadIdx.x;
    if (idx >= S_LEN * 32) return;
    int s = idx >> 5, d = idx & 31;
    float freq = powf(10000.0f, -(float)(2 * d) / 64.0f);
    float ang = (float)s * freq;
    cosb[idx] = cosf(ang);
    sinb[idx] = sinf(ang);
}

// rope one 8-elem fragment (4 even/odd pairs); scale folded into output
__device__ __forceinline__ short8 rope8(short8 v, float4 c, float4 s, float scale) {
    short8 o;
    const float* cp = (const float*)&c;
    const float* sp = (const float*)&s;
    #pragma unroll
    for (int m = 0; m < 4; m++) {
        float xe = b2f(v[2 * m]) * scale;
        float xo = b2f(v[2 * m + 1]) * scale;
        bf16 oe = __float2bfloat16(xe * cp[m] - xo * sp[m]);
        bf16 oo = __float2bfloat16(xe * sp[m] + xo * cp[m]);
        short se, so;
        __builtin_memcpy(&se, &oe, 2); __builtin_memcpy(&so, &oo, 2);
        o[2 * m] = se; o[2 * m + 1] = so;
    }
    return o;
}

// ======== 256x256 / BK=64 / 8-wave QKV GEMM — TRUE 8-PHASE SCHEDULE =========
// Per K-tile: 4 phases (C-quadrants, 16 MFMA each). B-frags read at q0, held
// in regs. Stage 1 half-tile/phase: q0->A_h0(t+1), q1->A_h1(t+1),
// q2->B_h0(t+2), q3->B_h1(t+2) (dest free: B region of CURRENT buf frees
// after q0; A region of other buf freed at prev group's q3). vmcnt(4) ONLY at
// q3 (before its barrier -> globalized): leaves B(t+2) in flight, guarantees
// tile t+1 fully landed. Addressing/swizzle/epilogue = R15 (verified).
__global__ __launch_bounds__(512, 1) void gemm_qkv256_kernel(
        const bf16* __restrict__ xb,
        const bf16* __restrict__ wq, const bf16* __restrict__ wk, const bf16* __restrict__ wv,
        const float* __restrict__ cosb, const float* __restrict__ sinb,
        bf16* __restrict__ qb, bf16* __restrict__ kb, bf16* __restrict__ vtb) {
    __shared__ bf16 As[2][256 * 64];
    __shared__ bf16 Bs[2][256 * 64];
    int tid = threadIdx.x;
    int lane = tid & 63, w = tid >> 6;
    int wr = w >> 2, wc = w & 3;
    int lhi = lane >> 4, llo = lane & 15;

    int by = blockIdx.y;
    const bf16* W; int n0, mode;
    if (by < 8)       { W = wq; n0 = by * 256;        mode = 0; }
    else if (by < 10) { W = wk; n0 = (by - 8) * 256;  mode = 2; }
    else              { W = wv; n0 = (by - 10) * 256; mode = 1; }
    int bx = blockIdx.x;
    int bxs = (bx & 7) * 2 + (bx >> 3);    // XCD swizzle, 16 tiles bijective
    int m0 = bxs * 256;

    const bf16* Abase = xb + (size_t)m0 * HID;
    const bf16* Bbase = W + (size_t)n0 * HID;

    // stage half-tile h (0:A_h0 1:A_h1 2:B_h0 3:B_h1) of k-tile kt into buf.
    // chunk gc in [h1*1024, h1*1024+1024): row=gc>>3, phys slot = (gc&7)^(row&7)
    // via pre-swizzled GLOBAL source; LDS dest linear (gload_lds rule).
    auto stage_half = [&](int buf, int kt, int h) {
        const bf16* mat = (h < 2) ? Abase : Bbase;
        bf16* ldsb = (h < 2) ? &As[buf][0] : &Bs[buf][0];
        int h1 = h & 1;
        #pragma unroll
        for (int q2 = 0; q2 < 2; q2++) {
            int gc = h1 * 1024 + q2 * 512 + tid;
            int row = gc >> 3;
            int sl = (gc & 7) ^ (row & 7);
            gload_lds16(mat + (size_t)row * HID + kt * 64 + sl * 8, ldsb + gc * 8);
        }
    };

    f32x4 acc[8][4] = {};
    const int nt = HID / 64;   // 32

    // prologue: tile 0 complete + B halves of tile 1 (steady-state rule's
    // group(-1) q2/q3 contribution). 12 loads; wait all but B(1)'s 4.
    stage_half(0, 0, 0); stage_half(0, 0, 1);
    stage_half(0, 0, 2); stage_half(0, 0, 3);
    stage_half(1, 1, 2); stage_half(1, 1, 3);
    asm volatile("s_waitcnt vmcnt(4)" ::: "memory");
    __builtin_amdgcn_s_barrier();

    for (int t = 0; t < nt; ++t) {
        int bt = t & 1;
        const bf16* Ac = &As[bt][0];
        const bf16* Bc = &Bs[bt][0];
        short8 bfr[4][2];
        #pragma unroll
        for (int q = 0; q < 4; q++) {
            // ---- ds reads for this phase ----
            if (q == 0) {
                #pragma unroll
                for (int j = 0; j < 4; j++) {
                    int row = wc * 64 + j * 16 + llo;
                    int x = row & 7;
                    bfr[j][0] = *(const short8*)(Bc + row * 64 + ((lhi ^ x) * 8));
                    bfr[j][1] = *(const short8*)(Bc + row * 64 + (((4 + lhi) ^ x) * 8));
                }
            }
            short8 a0[2], a1[2];
            #pragma unroll
            for (int i2 = 0; i2 < 2; i2++) {
                int row = wr * 128 + (q * 2 + i2) * 16 + llo;
                int x = row & 7;
                a0[i2] = *(const short8*)(Ac + row * 64 + ((lhi ^ x) * 8));
                a1[i2] = *(const short8*)(Ac + row * 64 + (((4 + lhi) ^ x) * 8));
            }
            // ---- stage one half-tile per the schedule ----
            if (q == 0) { if (t + 1 < nt) stage_half((t + 1) & 1, t + 1, 0); }
            else if (q == 1) { if (t + 1 < nt) stage_half((t + 1) & 1, t + 1, 1); }
            else if (q == 2) { if (t + 2 < nt) stage_half(bt, t + 2, 2); }
            else             { if (t + 2 < nt) stage_half(bt, t + 2, 3); }
            // ---- barrier; wait own ds reads; MFMA quadrant ----
            __builtin_amdgcn_s_barrier();
            asm volatile("s_waitcnt lgkmcnt(0)" ::: "memory");
            __builtin_amdgcn_sched_barrier(0);   // rule #18: pin MFMA below wait
            __builtin_amdgcn_s_setprio(1);
            #pragma unroll
            for (int i2 = 0; i2 < 2; i2++)
                #pragma unroll
                for (int j = 0; j < 4; j++) {
                    acc[q * 2 + i2][j] = MFMA16(a0[i2], bfr[j][0], acc[q * 2 + i2][j]);
                    acc[q * 2 + i2][j] = MFMA16(a1[i2], bfr[j][1], acc[q * 2 + i2][j]);
                }
            __builtin_amdgcn_s_setprio(0);
            if (q == 3)   // once per K-tile: tile t+1 landed; B(t+2) stays in flight
                asm volatile("s_waitcnt vmcnt(4)" ::: "memory");
            __builtin_amdgcn_s_barrier();
        }
    }

    // ---- epilogue (verified in R15) ----
    #pragma unroll
    for (int i = 0; i < 8; i++)
        #pragma unroll
        for (int j = 0; j < 4; j++) {
            int col = wc * 64 + j * 16 + llo;
            #pragma unroll
            for (int r = 0; r < 4; r++) {
                int m = m0 + wr * 128 + i * 16 + lhi * 4 + r;
                float v = acc[i][j][r];
                if (mode == 0) {
                    qb[(size_t)m * 2048 + n0 + col] = __float2bfloat16(v);
                } else if (mode == 1) {
                    int bb = m >> 11, ss = m & 2047;
                    vtb[((size_t)(bb * 512 + n0 + col)) * S_LEN + ss] = __float2bfloat16(v);
                } else {
                    int dcol = n0 + col;
                    int dd = dcol & 63;
                    int pidx = dd >> 1;
                    float sgn = (dd & 1) ? 1.0f : -1.0f;
                    int ss = m & 2047;
                    float c  = cosb[ss * 32 + pidx];
                    float sn = sinb[ss * 32 + pidx];
                    float o = __shfl_xor(v, 1, 64);
                    kb[(size_t)m * 512 + dcol] = __float2bfloat16(v * c + sgn * o * sn);
                }
            }
        }
}

// ---------------- GEMM core: 128x128 tile, BK=32, 3-buffer depth-2 pipeline --
// (kept for gemm_out)
__device__ __forceinline__ void gemm_core(const bf16* __restrict__ A,
                                          const bf16* __restrict__ W,
                                          int K, int m0, int n0,
                                          bf16* As, bf16* Bs,
                                          f32x4 acc[4][4]) {
    int tid = threadIdx.x;
    int lane = tid & 63, wid = tid >> 6;
    int wr = wid >> 1, wc = wid & 1;
    int lhi = lane >> 4, llo = lane & 15;
    int c0 = tid, c1 = tid + 256;
    int r0 = c0 >> 2, s0 = ((c0 & 3) ^ ((r0 >> 1) & 3)) * 8;
    int r1 = c1 >> 2, s1 = ((c1 & 3) ^ ((r1 >> 1) & 3)) * 8;
    const bf16* gA0 = A + (size_t)(m0 + r0) * K + s0;
    const bf16* gA1 = A + (size_t)(m0 + r1) * K + s1;
    const bf16* gB0 = W + (size_t)(n0 + r0) * K + s0;
    const bf16* gB1 = W + (size_t)(n0 + r1) * K + s1;

    auto stage = [&](int buf, int k0) {
        bf16* a = As + buf * 4096;
        bf16* b = Bs + buf * 4096;
        gload_lds16(gA0 + k0, a + c0 * 8);
        gload_lds16(gA1 + k0, a + c1 * 8);
        gload_lds16(gB0 + k0, b + c0 * 8);
        gload_lds16(gB1 + k0, b + c1 * 8);
    };
    auto compute = [&](int buf) {
        const bf16* Ac = As + buf * 4096;
        const bf16* Bc = Bs + buf * 4096;
        short8 af[4], bfr[4];
        #pragma unroll
        for (int i = 0; i < 4; i++) {
            int row = wr * 64 + i * 16 + llo;
            af[i] = *(const short8*)(Ac + row * 32 + ((lhi ^ ((row >> 1) & 3)) * 8));
        }
        #pragma unroll
        for (int j = 0; j < 4; j++) {
            int row = wc * 64 + j * 16 + llo;
            bfr[j] = *(const short8*)(Bc + row * 32 + ((lhi ^ ((row >> 1) & 3)) * 8));
        }
        __builtin_amdgcn_s_setprio(1);
        #pragma unroll
        for (int i = 0; i < 4; i++)
            #pragma unroll
            for (int j = 0; j < 4; j++)
                acc[i][j] = MFMA16(af[i], bfr[j], acc[i][j]);
        __builtin_amdgcn_s_setprio(0);
    };

    int nt = K / 32;
    stage(0, 0);
    stage(1, 32);
    int b0 = 0, b1 = 1, b2 = 2;
    for (int t = 0; t < nt - 1; ++t) {
        asm volatile("s_waitcnt vmcnt(4)" ::: "memory");
        __builtin_amdgcn_s_barrier();
        if (t + 2 < nt) stage(b2, (t + 2) * 32);
        __builtin_amdgcn_sched_barrier(0);
        compute(b0);
        int tmp = b0; b0 = b1; b1 = b2; b2 = tmp;
    }
    asm volatile("s_waitcnt vmcnt(0)" ::: "memory");
    __builtin_amdgcn_s_barrier();
    compute(b0);
}

// ---------------- output projection: fp32 out ----------------
__global__ __launch_bounds__(256) void gemm_out_kernel(
        const bf16* __restrict__ attnb, const bf16* __restrict__ wob,
        float* __restrict__ out) {
    __shared__ bf16 As[3 * 128 * 32];
    __shared__ bf16 Bs[3 * 128 * 32];
    int bx = blockIdx.x;
    int bxs = (bx & 7) * 4 + (bx >> 3);
    int m0 = bxs * 128;
    int n0 = blockIdx.y * 128;
    f32x4 acc[4][4] = {};
    gemm_core(attnb, wob, HID, m0, n0, As, Bs, acc);

    int lane = threadIdx.x & 63, wid = threadIdx.x >> 6;
    int wr = wid >> 1, wc = wid & 1;
    int lhi = lane >> 4, llo = lane & 15;
    #pragma unroll
    for (int i = 0; i < 4; i++)
        #pragma unroll
        for (int j = 0; j < 4; j++) {
            int col = wc * 64 + j * 16 + llo;
            #pragma unroll
            for (int r = 0; r < 4; r++) {
                int row = wr * 64 + i * 16 + lhi * 4 + r;
                out[(size_t)(m0 + row) * HID + n0 + col] = acc[i][j][r];
            }
        }
}

// ---------------- flash attention: swapped-QK^T, in-lane-row softmax (R12) --
__global__ __launch_bounds__(256, 4) void flash_kernel(
        const bf16* __restrict__ qb, const bf16* __restrict__ kb,
        const bf16* __restrict__ vtb, const float* __restrict__ cosb,
        const float* __restrict__ sinb, bf16* __restrict__ attnb) {
    __shared__ bf16 Ks[2][64 * 64];
    __shared__ bf16 Vs[2][64 * 64];
    __shared__ bf16 Pl[4][16 * 64];
    int bh = blockIdx.y;
    int b = bh >> 5, h = bh & 31;
    int kvh = h >> 2;
    int tid = threadIdx.x;
    int wid = tid >> 6, lane = tid & 63;
    int lhi = lane >> 4, llo = lane & 15;

    const bf16* Kg = kb + (size_t)(b * S_LEN) * KVD + kvh * HD;
    const bf16* Vg = vtb + (size_t)(b * 512 + kvh * 64) * S_LEN;

    int c0 = tid, c1 = tid + 256;
    int r0 = c0 >> 3, s0 = ((c0 & 7) ^ (r0 & 7)) * 8;
    int r1 = c1 >> 3, s1 = ((c1 & 7) ^ (r1 & 7)) * 8;

    bf16* pl = &Pl[wid][0];
    const int xw = llo & 7;
    const int hh = lhi >> 1;
    bf16* pwb = pl + llo * 64 + (lhi & 1) * 4;
    const int prd0 = llo * 64 + ((lhi ^ xw) * 8);
    const int prd1 = llo * 64 + (((lhi + 4) ^ xw) * 8);

    auto stage = [&](int buf, int t0) {
        gload_lds16(Kg + (size_t)(t0 + r0) * KVD + s0, &Ks[buf][c0 * 8]);
        gload_lds16(Kg + (size_t)(t0 + r1) * KVD + s1, &Ks[buf][c1 * 8]);
        gload_lds16(Vg + (size_t)r0 * S_LEN + t0 + s0, &Vs[buf][c0 * 8]);
        gload_lds16(Vg + (size_t)r1 * S_LEN + t0 + s1, &Vs[buf][c1 * 8]);
    };

    auto run_phase = [&](int j) {
        int qrow0 = j * 64 + wid * 16;
        int spos = qrow0 + llo;
        const bf16* qrow = qb + ((size_t)(b * S_LEN) + spos) * (NH * HD) + h * HD;
        float4 cv0 = *(const float4*)(cosb + spos * 32 + lhi * 4);
        float4 sv0 = *(const float4*)(sinb + spos * 32 + lhi * 4);
        float4 cv1 = *(const float4*)(cosb + spos * 32 + 16 + lhi * 4);
        float4 sv1 = *(const float4*)(sinb + spos * 32 + 16 + lhi * 4);
        short8 qf0 = rope8(*(const short8*)(qrow + lhi * 8), cv0, sv0, QSCALE);
        short8 qf1 = rope8(*(const short8*)(qrow + 32 + lhi * 8), cv1, sv1, QSCALE);

        f32x4 acc[4] = {};
        float psum = 0.f;
        int qloc = wid * 16 + llo;

        stage(0, 0);
        asm volatile("s_waitcnt vmcnt(0)" ::: "memory");
        __builtin_amdgcn_s_barrier();
        int cur = 0;
        for (int t = 0; t <= j; ++t) {
            int t0 = t * 64;
            if (t < j) stage(cur ^ 1, t0 + 64);
            const bf16* Kc = &Ks[cur][0];
            const bf16* Vc = &Vs[cur][0];
            f32x4 z[4];
            __builtin_amdgcn_s_setprio(1);
            #pragma unroll
            for (int cb = 0; cb < 4; cb++) {
                int row = cb * 16 + llo;
                short8 k0 = *(const short8*)(Kc + row * 64 + ((lhi ^ xw) * 8));
                short8 k1 = *(const short8*)(Kc + row * 64 + (((lhi + 4) ^ xw) * 8));
                f32x4 zz = {0.f, 0.f, 0.f, 0.f};
                zz = MFMA16(k0, qf0, zz);
                zz = MFMA16(k1, qf1, zz);
                z[cb] = zz;
            }
            __builtin_amdgcn_s_setprio(0);
            bool diag = (t == j);
            #pragma unroll
            for (int cb = 0; cb < 4; cb++) {
                float p0 = __expf(z[cb][0]);
                float p1 = __expf(z[cb][1]);
                float p2 = __expf(z[cb][2]);
                float p3 = __expf(z[cb][3]);
                if (diag) {
                    int kl = cb * 16 + lhi * 4;
                    p0 = (kl + 0 <= qloc) ? p0 : 0.f;
                    p1 = (kl + 1 <= qloc) ? p1 : 0.f;
                    p2 = (kl + 2 <= qloc) ? p2 : 0.f;
                    p3 = (kl + 3 <= qloc) ? p3 : 0.f;
                }
                psum += (p0 + p1) + (p2 + p3);
                bf16 tmp[4];
                tmp[0] = __float2bfloat16(p0); tmp[1] = __float2bfloat16(p1);
                tmp[2] = __float2bfloat16(p2); tmp[3] = __float2bfloat16(p3);
                *(uint2*)(pwb + (((2 * cb + hh) ^ xw) * 8)) = *(uint2*)tmp;
            }
            short8 pa0 = *(const short8*)(pl + prd0);
            short8 pa1 = *(const short8*)(pl + prd1);
            __builtin_amdgcn_s_setprio(1);
            #pragma unroll
            for (int jb = 0; jb < 4; jb++) {
                int row = jb * 16 + llo;
                short8 v0 = *(const short8*)(Vc + row * 64 + ((lhi ^ xw) * 8));
                short8 v1 = *(const short8*)(Vc + row * 64 + (((lhi + 4) ^ xw) * 8));
                acc[jb] = MFMA16(pa0, v0, acc[jb]);
                acc[jb] = MFMA16(pa1, v1, acc[jb]);
            }
            __builtin_amdgcn_s_setprio(0);
            asm volatile("s_waitcnt vmcnt(0)" ::: "memory");
            __builtin_amdgcn_s_barrier();
            cur ^= 1;
        }
        psum += __shfl_xor(psum, 16, 64);
        psum += __shfl_xor(psum, 32, 64);
        float inv[4];
        #pragma unroll
        for (int r = 0; r < 4; r++)
            inv[r] = 1.0f / __shfl(psum, lhi * 4 + r, 64);
        size_t obase = ((size_t)(b * S_LEN) + qrow0) * (NH * HD) + h * HD;
        #pragma unroll
        for (int jb = 0; jb < 4; jb++)
            #pragma unroll
            for (int r = 0; r < 4; r++)
                attnb[obase + (size_t)(lhi * 4 + r) * (NH * HD) + jb * 16 + llo] =
                    __float2bfloat16(acc[jb][r] * inv[r]);
    };

    run_phase(blockIdx.x);
    run_phase(31 - blockIdx.x);
}

// ---------------- launcher ----------------
extern "C" void kernel_launch(void* const* d_in, const int* in_sizes, int n_in,
                              void* d_out, int out_size, void* d_ws, size_t ws_size,
                              hipStream_t stream) {
    const float* x  = (const float*)d_in[0];
    const float* wq = (const float*)d_in[1];
    const float* wk = (const float*)d_in[2];
    const float* wv = (const float*)d_in[3];
    const float* wo = (const float*)d_in[4];
    float* out = (float*)d_out;

    char* ws = (char*)d_ws;
    size_t off = 0;
    auto alloc = [&](size_t bytes) { void* p = ws + off; off += (bytes + 255) & ~(size_t)255; return p; };
    // NOTE: xb..wob must stay CONTIGUOUS (cast_all writes them as one region)
    bf16* xb   = (bf16*)alloc((size_t)M_TOT * HID * 2);
    bf16* wqb  = (bf16*)alloc((size_t)HID * HID * 2);
    bf16* wkb  = (bf16*)alloc((size_t)512 * HID * 2);
    bf16* wvb  = (bf16*)alloc((size_t)512 * HID * 2);
    bf16* wob  = (bf16*)alloc((size_t)HID * HID * 2);
    bf16* qb   = (bf16*)alloc((size_t)M_TOT * 2048 * 2);
    bf16* kb   = (bf16*)alloc((size_t)M_TOT * 512 * 2);
    bf16* vtb  = (bf16*)alloc((size_t)M_TOT * 512 * 2);
    bf16* attnb= (bf16*)alloc((size_t)M_TOT * 2048 * 2);
    float* cosb= (float*)alloc((size_t)S_LEN * 32 * 4);
    float* sinb= (float*)alloc((size_t)S_LEN * 32 * 4);

    cast_all_kernel<<<2048, 256, 0, stream>>>(x, wq, wk, wv, wo, xb);

    rope_tables_kernel<<<(S_LEN * 32 + 255) / 256, 256, 0, stream>>>(cosb, sinb);

    gemm_qkv256_kernel<<<dim3(16, 12), 512, 0, stream>>>(xb, wqb, wkb, wvb,
                                                         cosb, sinb, qb, kb, vtb);

    flash_kernel<<<dim3(16, BATCH * NH), 256, 0, stream>>>(qb, kb, vtb, cosb, sinb, attnb);

    gemm_out_kernel<<<dim3(M_TOT / 128, HID / 128), 256, 0, stream>>>(attnb, wob, out);
}

// Round 17
// 191.415 us; speedup vs baseline: 1.1261x; 1.1188x over previous
//
#include <hip/hip_runtime.h>
#include <hip/hip_bf16.h>

typedef __hip_bfloat16 bf16;
typedef __attribute__((ext_vector_type(8))) short short8;
typedef __attribute__((ext_vector_type(4))) float f32x4;

#define S_LEN 2048
#define BATCH 2
#define M_TOT 4096   // BATCH*S_LEN
#define HID 2048
#define NH 32
#define NKV 8
#define HD 64
#define KVD 512      // NKV*HD
#define QSCALE 0.125f

#define MFMA16(a, b, c) __builtin_amdgcn_mfma_f32_16x16x32_bf16(a, b, c, 0, 0, 0)

__device__ __forceinline__ void gload_lds16(const bf16* g, bf16* l) {
    __builtin_amdgcn_global_load_lds((const __attribute__((address_space(1))) void*)g,
                                     (__attribute__((address_space(3))) void*)l,
                                     16, 0, 0);
}

__device__ __forceinline__ float b2f(short v) {
    unsigned u = ((unsigned)(unsigned short)v) << 16;
    float f; __builtin_memcpy(&f, &u, 4); return f;
}

// ------- merged cast fp32->bf16 (5 inputs) + RoPE table build --------------
#define N8_X   1048576   // 4096*2048/8
#define N8_WQ   524288   // 2048*2048/8
#define N8_WK   131072   // 512*2048/8
#define N8_TOT 2359296   // x+wq+wk+wv+wo
#define NTBL   65536     // S_LEN*32 table entries
__global__ void cast_all_kernel(const float* __restrict__ x, const float* __restrict__ wq,
                                const float* __restrict__ wk, const float* __restrict__ wv,
                                const float* __restrict__ wo, bf16* __restrict__ dst,
                                float* __restrict__ cosb, float* __restrict__ sinb) {
    int stride = gridDim.x * blockDim.x;
    for (int i = blockIdx.x * blockDim.x + threadIdx.x; i < N8_TOT + NTBL; i += stride) {
        if (i >= N8_TOT) {
            int idx = i - N8_TOT;
            int s = idx >> 5, d = idx & 31;
            float freq = powf(10000.0f, -(float)(2 * d) / 64.0f);
            float ang = (float)s * freq;
            cosb[idx] = cosf(ang);
            sinb[idx] = sinf(ang);
            continue;
        }
        const float* s; int off;
        if (i < N8_X)                        { s = x;  off = i; }
        else if (i < N8_X + N8_WQ)           { s = wq; off = i - N8_X; }
        else if (i < N8_X + N8_WQ + N8_WK)   { s = wk; off = i - (N8_X + N8_WQ); }
        else if (i < N8_X + N8_WQ + 2*N8_WK) { s = wv; off = i - (N8_X + N8_WQ + N8_WK); }
        else                                 { s = wo; off = i - (N8_X + N8_WQ + 2*N8_WK); }
        const float4* sp = (const float4*)(s + (size_t)off * 8);
        float4 a = sp[0], b = sp[1];
        bf16 tmp[8];
        tmp[0] = __float2bfloat16(a.x); tmp[1] = __float2bfloat16(a.y);
        tmp[2] = __float2bfloat16(a.z); tmp[3] = __float2bfloat16(a.w);
        tmp[4] = __float2bfloat16(b.x); tmp[5] = __float2bfloat16(b.y);
        tmp[6] = __float2bfloat16(b.z); tmp[7] = __float2bfloat16(b.w);
        *(short8*)(dst + (size_t)i * 8) = *(short8*)tmp;
    }
}

// rope one 8-elem fragment (4 even/odd pairs); scale folded into output
__device__ __forceinline__ short8 rope8(short8 v, float4 c, float4 s, float scale) {
    short8 o;
    const float* cp = (const float*)&c;
    const float* sp = (const float*)&s;
    #pragma unroll
    for (int m = 0; m < 4; m++) {
        float xe = b2f(v[2 * m]) * scale;
        float xo = b2f(v[2 * m + 1]) * scale;
        bf16 oe = __float2bfloat16(xe * cp[m] - xo * sp[m]);
        bf16 oo = __float2bfloat16(xe * sp[m] + xo * cp[m]);
        short se, so;
        __builtin_memcpy(&se, &oe, 2); __builtin_memcpy(&so, &oo, 2);
        o[2 * m] = se; o[2 * m + 1] = so;
    }
    return o;
}

// ---------------- GEMM core: 128x128 tile, BK=32, 3-buffer depth-2 pipeline --
// stage(t+2) issued right after the barrier, BEFORE compute(t); counted
// vmcnt(4) keeps the next tile's loads in flight across the barrier (T4).
__device__ __forceinline__ void gemm_core(const bf16* __restrict__ A,
                                          const bf16* __restrict__ W,
                                          int K, int m0, int n0,
                                          bf16* As, bf16* Bs,
                                          f32x4 acc[4][4]) {
    int tid = threadIdx.x;
    int lane = tid & 63, wid = tid >> 6;
    int wr = wid >> 1, wc = wid & 1;
    int lhi = lane >> 4, llo = lane & 15;
    int c0 = tid, c1 = tid + 256;
    int r0 = c0 >> 2, s0 = ((c0 & 3) ^ ((r0 >> 1) & 3)) * 8;
    int r1 = c1 >> 2, s1 = ((c1 & 3) ^ ((r1 >> 1) & 3)) * 8;
    const bf16* gA0 = A + (size_t)(m0 + r0) * K + s0;
    const bf16* gA1 = A + (size_t)(m0 + r1) * K + s1;
    const bf16* gB0 = W + (size_t)(n0 + r0) * K + s0;
    const bf16* gB1 = W + (size_t)(n0 + r1) * K + s1;

    auto stage = [&](int buf, int k0) {
        bf16* a = As + buf * 4096;
        bf16* b = Bs + buf * 4096;
        gload_lds16(gA0 + k0, a + c0 * 8);
        gload_lds16(gA1 + k0, a + c1 * 8);
        gload_lds16(gB0 + k0, b + c0 * 8);
        gload_lds16(gB1 + k0, b + c1 * 8);
    };
    auto compute = [&](int buf) {
        const bf16* Ac = As + buf * 4096;
        const bf16* Bc = Bs + buf * 4096;
        short8 af[4], bfr[4];
        #pragma unroll
        for (int i = 0; i < 4; i++) {
            int row = wr * 64 + i * 16 + llo;
            af[i] = *(const short8*)(Ac + row * 32 + ((lhi ^ ((row >> 1) & 3)) * 8));
        }
        #pragma unroll
        for (int j = 0; j < 4; j++) {
            int row = wc * 64 + j * 16 + llo;
            bfr[j] = *(const short8*)(Bc + row * 32 + ((lhi ^ ((row >> 1) & 3)) * 8));
        }
        __builtin_amdgcn_s_setprio(1);
        #pragma unroll
        for (int i = 0; i < 4; i++)
            #pragma unroll
            for (int j = 0; j < 4; j++)
                acc[i][j] = MFMA16(af[i], bfr[j], acc[i][j]);
        __builtin_amdgcn_s_setprio(0);
    };

    int nt = K / 32;
    stage(0, 0);
    stage(1, 32);
    int b0 = 0, b1 = 1, b2 = 2;
    for (int t = 0; t < nt - 1; ++t) {
        asm volatile("s_waitcnt vmcnt(4)" ::: "memory");   // stage(t) done; t+1 in flight
        __builtin_amdgcn_s_barrier();
        if (t + 2 < nt) stage(b2, (t + 2) * 32);           // issue EARLY: max flight time
        __builtin_amdgcn_sched_barrier(0);                 // pin issue point above compute
        compute(b0);
        int tmp = b0; b0 = b1; b1 = b2; b2 = tmp;
    }
    asm volatile("s_waitcnt vmcnt(0)" ::: "memory");       // last tile
    __builtin_amdgcn_s_barrier();
    compute(b0);
}

// ---------------- fused QKV projection (RoPE fused into K epilogue) ----------
__global__ __launch_bounds__(256) void gemm_qkv_kernel(
        const bf16* __restrict__ xb,
        const bf16* __restrict__ wq, const bf16* __restrict__ wk, const bf16* __restrict__ wv,
        const float* __restrict__ cosb, const float* __restrict__ sinb,
        bf16* __restrict__ qb, bf16* __restrict__ kb, bf16* __restrict__ vtb) {
    __shared__ bf16 As[3 * 128 * 32];
    __shared__ bf16 Bs[3 * 128 * 32];
    int by = blockIdx.y;
    const bf16* W; bf16* Cb; int n0, ldc, mode;
    if (by < 16)      { W = wq; Cb = qb;  n0 = by * 128;        ldc = 2048; mode = 0; }
    else if (by < 20) { W = wk; Cb = kb;  n0 = (by - 16) * 128; ldc = 512;  mode = 2; }
    else              { W = wv; Cb = vtb; n0 = (by - 20) * 128; ldc = 0;    mode = 1; }
    int bx = blockIdx.x;
    int bxs = (bx & 7) * 4 + (bx >> 3);    // XCD-aware m-swizzle (32 tiles, 8 XCDs)
    int m0 = bxs * 128;

    f32x4 acc[4][4] = {};
    gemm_core(xb, W, HID, m0, n0, As, Bs, acc);

    int lane = threadIdx.x & 63, wid = threadIdx.x >> 6;
    int wr = wid >> 1, wc = wid & 1;
    int lhi = lane >> 4, llo = lane & 15;
    #pragma unroll
    for (int i = 0; i < 4; i++)
        #pragma unroll
        for (int j = 0; j < 4; j++) {
            int col = wc * 64 + j * 16 + llo;
            #pragma unroll
            for (int r = 0; r < 4; r++) {
                int row = wr * 64 + i * 16 + lhi * 4 + r;
                int m = m0 + row;
                float v = acc[i][j][r];
                if (mode == 0) {
                    Cb[(size_t)m * ldc + n0 + col] = __float2bfloat16(v);
                } else if (mode == 1) {
                    int bb = m >> 11, ss = m & 2047;
                    Cb[((size_t)(bb * 512 + n0 + col)) * S_LEN + ss] = __float2bfloat16(v);
                } else {
                    // K with fused RoPE: pair partner is adjacent lane (col^1)
                    int dcol = n0 + col;
                    int dd = dcol & 63;
                    int pidx = dd >> 1;
                    float sgn = (dd & 1) ? 1.0f : -1.0f;
                    int ss = m & 2047;
                    float c  = cosb[ss * 32 + pidx];
                    float sn = sinb[ss * 32 + pidx];
                    float o = __shfl_xor(v, 1, 64);
                    float outv = v * c + sgn * o * sn;
                    Cb[(size_t)m * 512 + dcol] = __float2bfloat16(outv);
                }
            }
        }
}

// ---------------- output projection: fp32 out ----------------
__global__ __launch_bounds__(256) void gemm_out_kernel(
        const bf16* __restrict__ attnb, const bf16* __restrict__ wob,
        float* __restrict__ out) {
    __shared__ bf16 As[3 * 128 * 32];
    __shared__ bf16 Bs[3 * 128 * 32];
    int bx = blockIdx.x;
    int bxs = (bx & 7) * 4 + (bx >> 3);
    int m0 = bxs * 128;
    int n0 = blockIdx.y * 128;
    f32x4 acc[4][4] = {};
    gemm_core(attnb, wob, HID, m0, n0, As, Bs, acc);

    int lane = threadIdx.x & 63, wid = threadIdx.x >> 6;
    int wr = wid >> 1, wc = wid & 1;
    int lhi = lane >> 4, llo = lane & 15;
    #pragma unroll
    for (int i = 0; i < 4; i++)
        #pragma unroll
        for (int j = 0; j < 4; j++) {
            int col = wc * 64 + j * 16 + llo;
            #pragma unroll
            for (int r = 0; r < 4; r++) {
                int row = wr * 64 + i * 16 + lhi * 4 + r;
                out[(size_t)(m0 + row) * HID + n0 + col] = acc[i][j][r];
            }
        }
}

// ---------------- flash attention: swapped-QK^T, in-lane-row softmax (R12) --
__global__ __launch_bounds__(256, 4) void flash_kernel(
        const bf16* __restrict__ qb, const bf16* __restrict__ kb,
        const bf16* __restrict__ vtb, const float* __restrict__ cosb,
        const float* __restrict__ sinb, bf16* __restrict__ attnb) {
    __shared__ bf16 Ks[2][64 * 64];
    __shared__ bf16 Vs[2][64 * 64];
    __shared__ bf16 Pl[4][16 * 64];
    int bh = blockIdx.y;
    int b = bh >> 5, h = bh & 31;
    int kvh = h >> 2;
    int tid = threadIdx.x;
    int wid = tid >> 6, lane = tid & 63;
    int lhi = lane >> 4, llo = lane & 15;

    const bf16* Kg = kb + (size_t)(b * S_LEN) * KVD + kvh * HD;
    const bf16* Vg = vtb + (size_t)(b * 512 + kvh * 64) * S_LEN;

    int c0 = tid, c1 = tid + 256;
    int r0 = c0 >> 3, s0 = ((c0 & 7) ^ (r0 & 7)) * 8;
    int r1 = c1 >> 3, s1 = ((c1 & 7) ^ (r1 & 7)) * 8;

    bf16* pl = &Pl[wid][0];
    const int xw = llo & 7;
    const int hh = lhi >> 1;
    bf16* pwb = pl + llo * 64 + (lhi & 1) * 4;
    const int prd0 = llo * 64 + ((lhi ^ xw) * 8);
    const int prd1 = llo * 64 + (((lhi + 4) ^ xw) * 8);

    auto stage = [&](int buf, int t0) {
        gload_lds16(Kg + (size_t)(t0 + r0) * KVD + s0, &Ks[buf][c0 * 8]);
        gload_lds16(Kg + (size_t)(t0 + r1) * KVD + s1, &Ks[buf][c1 * 8]);
        gload_lds16(Vg + (size_t)r0 * S_LEN + t0 + s0, &Vs[buf][c0 * 8]);
        gload_lds16(Vg + (size_t)r1 * S_LEN + t0 + s1, &Vs[buf][c1 * 8]);
    };

    auto run_phase = [&](int j) {
        int qrow0 = j * 64 + wid * 16;
        int spos = qrow0 + llo;
        const bf16* qrow = qb + ((size_t)(b * S_LEN) + spos) * (NH * HD) + h * HD;
        float4 cv0 = *(const float4*)(cosb + spos * 32 + lhi * 4);
        float4 sv0 = *(const float4*)(sinb + spos * 32 + lhi * 4);
        float4 cv1 = *(const float4*)(cosb + spos * 32 + 16 + lhi * 4);
        float4 sv1 = *(const float4*)(sinb + spos * 32 + 16 + lhi * 4);
        short8 qf0 = rope8(*(const short8*)(qrow + lhi * 8), cv0, sv0, QSCALE);
        short8 qf1 = rope8(*(const short8*)(qrow + 32 + lhi * 8), cv1, sv1, QSCALE);

        f32x4 acc[4] = {};
        float psum = 0.f;
        int qloc = wid * 16 + llo;

        stage(0, 0);
        asm volatile("s_waitcnt vmcnt(0)" ::: "memory");
        __builtin_amdgcn_s_barrier();
        int cur = 0;
        for (int t = 0; t <= j; ++t) {
            int t0 = t * 64;
            if (t < j) stage(cur ^ 1, t0 + 64);
            const bf16* Kc = &Ks[cur][0];
            const bf16* Vc = &Vs[cur][0];
            f32x4 z[4];
            __builtin_amdgcn_s_setprio(1);
            #pragma unroll
            for (int cb = 0; cb < 4; cb++) {
                int row = cb * 16 + llo;
                short8 k0 = *(const short8*)(Kc + row * 64 + ((lhi ^ xw) * 8));
                short8 k1 = *(const short8*)(Kc + row * 64 + (((lhi + 4) ^ xw) * 8));
                f32x4 zz = {0.f, 0.f, 0.f, 0.f};
                zz = MFMA16(k0, qf0, zz);
                zz = MFMA16(k1, qf1, zz);
                z[cb] = zz;
            }
            __builtin_amdgcn_s_setprio(0);
            bool diag = (t == j);
            #pragma unroll
            for (int cb = 0; cb < 4; cb++) {
                float p0 = __expf(z[cb][0]);
                float p1 = __expf(z[cb][1]);
                float p2 = __expf(z[cb][2]);
                float p3 = __expf(z[cb][3]);
                if (diag) {
                    int kl = cb * 16 + lhi * 4;
                    p0 = (kl + 0 <= qloc) ? p0 : 0.f;
                    p1 = (kl + 1 <= qloc) ? p1 : 0.f;
                    p2 = (kl + 2 <= qloc) ? p2 : 0.f;
                    p3 = (kl + 3 <= qloc) ? p3 : 0.f;
                }
                psum += (p0 + p1) + (p2 + p3);
                bf16 tmp[4];
                tmp[0] = __float2bfloat16(p0); tmp[1] = __float2bfloat16(p1);
                tmp[2] = __float2bfloat16(p2); tmp[3] = __float2bfloat16(p3);
                *(uint2*)(pwb + (((2 * cb + hh) ^ xw) * 8)) = *(uint2*)tmp;
            }
            short8 pa0 = *(const short8*)(pl + prd0);
            short8 pa1 = *(const short8*)(pl + prd1);
            __builtin_amdgcn_s_setprio(1);
            #pragma unroll
            for (int jb = 0; jb < 4; jb++) {
                int row = jb * 16 + llo;
                short8 v0 = *(const short8*)(Vc + row * 64 + ((lhi ^ xw) * 8));
                short8 v1 = *(const short8*)(Vc + row * 64 + (((lhi + 4) ^ xw) * 8));
                acc[jb] = MFMA16(pa0, v0, acc[jb]);
                acc[jb] = MFMA16(pa1, v1, acc[jb]);
            }
            __builtin_amdgcn_s_setprio(0);
            asm volatile("s_waitcnt vmcnt(0)" ::: "memory");
            __builtin_amdgcn_s_barrier();
            cur ^= 1;
        }
        psum += __shfl_xor(psum, 16, 64);
        psum += __shfl_xor(psum, 32, 64);
        float inv[4];
        #pragma unroll
        for (int r = 0; r < 4; r++)
            inv[r] = 1.0f / __shfl(psum, lhi * 4 + r, 64);
        size_t obase = ((size_t)(b * S_LEN) + qrow0) * (NH * HD) + h * HD;
        #pragma unroll
        for (int jb = 0; jb < 4; jb++)
            #pragma unroll
            for (int r = 0; r < 4; r++)
                attnb[obase + (size_t)(lhi * 4 + r) * (NH * HD) + jb * 16 + llo] =
                    __float2bfloat16(acc[jb][r] * inv[r]);
    };

    run_phase(blockIdx.x);
    run_phase(31 - blockIdx.x);
}

// ---------------- launcher ----------------
extern "C" void kernel_launch(void* const* d_in, const int* in_sizes, int n_in,
                              void* d_out, int out_size, void* d_ws, size_t ws_size,
                              hipStream_t stream) {
    const float* x  = (const float*)d_in[0];
    const float* wq = (const float*)d_in[1];
    const float* wk = (const float*)d_in[2];
    const float* wv = (const float*)d_in[3];
    const float* wo = (const float*)d_in[4];
    float* out = (float*)d_out;

    char* ws = (char*)d_ws;
    size_t off = 0;
    auto alloc = [&](size_t bytes) { void* p = ws + off; off += (bytes + 255) & ~(size_t)255; return p; };
    // NOTE: xb..wob must stay CONTIGUOUS (cast_all writes them as one region)
    bf16* xb   = (bf16*)alloc((size_t)M_TOT * HID * 2);
    bf16* wqb  = (bf16*)alloc((size_t)HID * HID * 2);
    bf16* wkb  = (bf16*)alloc((size_t)512 * HID * 2);
    bf16* wvb  = (bf16*)alloc((size_t)512 * HID * 2);
    bf16* wob  = (bf16*)alloc((size_t)HID * HID * 2);
    bf16* qb   = (bf16*)alloc((size_t)M_TOT * 2048 * 2);
    bf16* kb   = (bf16*)alloc((size_t)M_TOT * 512 * 2);
    bf16* vtb  = (bf16*)alloc((size_t)M_TOT * 512 * 2);
    bf16* attnb= (bf16*)alloc((size_t)M_TOT * 2048 * 2);
    float* cosb= (float*)alloc((size_t)S_LEN * 32 * 4);
    float* sinb= (float*)alloc((size_t)S_LEN * 32 * 4);

    cast_all_kernel<<<2048, 256, 0, stream>>>(x, wq, wk, wv, wo, xb, cosb, sinb);

    gemm_qkv_kernel<<<dim3(M_TOT / 128, 24), 256, 0, stream>>>(xb, wqb, wkb, wvb,
                                                               cosb, sinb, qb, kb, vtb);

    flash_kernel<<<dim3(16, BATCH * NH), 256, 0, stream>>>(qb, kb, vtb, cosb, sinb, attnb);

    gemm_out_kernel<<<dim3(M_TOT / 128, HID / 128), 256, 0, stream>>>(attnb, wob, out);
}